// Round 1
// baseline (609.238 us; speedup 1.0000x reference)
//
#include <hip/hip_runtime.h>
#include <hip/hip_bf16.h>

typedef __bf16 bf16_t;
typedef __bf16 bf16x4 __attribute__((ext_vector_type(4)));
typedef __bf16 bf16x8 __attribute__((ext_vector_type(8)));
typedef float  f32x4  __attribute__((ext_vector_type(4)));

#define NB      32      // batch
#define NPIX    4096    // 64*64 pixels per sample
#define CIN     512
#define FOUT    512
#define TM      128
#define TN      128
#define BK      32

// async global->LDS, 16B per lane. LDS dest must be wave-uniform (HW: base + lane*16).
__device__ __forceinline__ void async_copy16(const void* gsrc, void* ldsdst) {
    __builtin_amdgcn_global_load_lds(
        (const __attribute__((address_space(1))) unsigned int*)gsrc,
        (__attribute__((address_space(3))) unsigned int*)ldsdst,
        16, 0, 0);
}

// ---------------------------------------------------------------------------
// Pass 1: gather per-batch class weights, transpose [k][n] -> [n][k], cvt bf16.
// wsB[b][n][k] = (bf16) kernel[cls[b]][k][n]
// grid (16 n-tiles, 16 k-tiles, 32 batches), block (32,8)
// ---------------------------------------------------------------------------
__global__ __launch_bounds__(256) void gather_w_kernel(
    const float* __restrict__ kern, const int* __restrict__ cls,
    bf16_t* __restrict__ wsB)
{
    __shared__ float tile[32][33];
    const int n0 = blockIdx.x * 32;
    const int k0 = blockIdx.y * 32;
    const int b  = blockIdx.z;
    const int c  = cls[b];
    const int tx = threadIdx.x;      // 0..31
    const int ty = threadIdx.y;      // 0..7

    const float* src = kern + (long)c * CIN * FOUT;
#pragma unroll
    for (int i = 0; i < 4; i++) {
        int k = k0 + ty + i * 8;
        tile[ty + i * 8][tx] = src[(long)k * FOUT + n0 + tx];
    }
    __syncthreads();
    bf16_t* dst = wsB + (long)b * FOUT * CIN;
#pragma unroll
    for (int i = 0; i < 4; i++) {
        int n = n0 + ty + i * 8;
        dst[(long)n * CIN + k0 + tx] = (bf16_t)tile[tx][ty + i * 8];
    }
}

// ---------------------------------------------------------------------------
// Pass 2: per-batch GEMM. out[b,p,f] = sum_c x[b,p,c] * wsB[b,f,c] + bias[cls[b],f]
// m97 structure: 128x128 tile, BK=32, global_load_lds(16B) staging for A(f32)+B(bf16),
// XOR-swizzled LDS (pre-swizzled global source + swizzled ds_read), XCD bid swizzle.
// 4 waves, each 64x64 via 4x4 of mfma_f32_16x16x32_bf16.
// ---------------------------------------------------------------------------
__global__ __launch_bounds__(256) void cond_conv_gemm(
    const float*  __restrict__ x,
    const bf16_t* __restrict__ wsB,
    const float*  __restrict__ bias,
    const int*    __restrict__ cls,
    float*        __restrict__ out)
{
    __shared__ float  AsF[TM * BK];     // [m][k] fp32, linear (swizzled content)
    __shared__ bf16_t BsH[TN * BK];     // [n][k] bf16, linear (swizzled content)

    // XCD-chunked swizzle: grid=4096, 8 XCDs, 512 logical blocks per XCD.
    // Consecutive LOGICAL blocks (sharing an A tile / a batch's wsB panel)
    // land on the same XCD -> re-reads hit that XCD's L2.
    const int hw  = blockIdx.x;
    const int bid = (hw & 7) * 512 + (hw >> 3);

    const int n_t = bid & 3;            // 4 n-tiles (fastest: adjacent share A tile)
    const int m_t = (bid >> 2) & 31;    // 32 m-tiles
    const int b   = bid >> 7;           // 32 batches

    const long x_base = (long)b * NPIX * CIN + (long)m_t * TM * CIN;
    const long w_base = (long)b * FOUT * CIN;
    const int  n0     = n_t * TN;

    const int t    = threadIdx.x;
    const int wave = t >> 6;
    const int lane = t & 63;
    const int wm   = (wave >> 1) * 64;  // wave m-offset in tile
    const int wn   = (wave & 1) * 64;   // wave n-offset in tile
    const int l15  = lane & 15;
    const int quad = lane >> 4;

    f32x4 acc[4][4];
#pragma unroll
    for (int i = 0; i < 4; i++)
#pragma unroll
        for (int j = 0; j < 4; j++)
            acc[i][j] = (f32x4){0.f, 0.f, 0.f, 0.f};

    // Per-lane staging coords (constant across K-steps and issues):
    // A: lane covers physical 16B slot p=lane&7 of row m; row m&7 == lane>>3.
    //    It must FETCH logical slot s = p ^ (m&7)  (involution; read applies same XOR).
    const int a_row_in_g = wave * 8 + (lane >> 3);          // + g*32
    const int a_kc       = ((lane & 7) ^ (lane >> 3)) << 2; // float offset in row
    // B: slot p=lane&3 of row n; n&3 == (lane>>2)&3.
    const int b_row_in_g = wave * 16 + (lane >> 2);         // + g*64
    const int b_kc       = ((lane & 3) ^ ((lane >> 2) & 3)) << 3; // bf16 offset

    for (int k0 = 0; k0 < CIN; k0 += BK) {
        // ---- stage A: 128x32 fp32, 4 issues x 16B/lane, direct to LDS ----
#pragma unroll
        for (int g = 0; g < 4; g++) {
            async_copy16(x + x_base + (long)(g * 32 + a_row_in_g) * CIN + k0 + a_kc,
                         (char*)AsF + g * 4096 + wave * 1024);
        }
        // ---- stage B: 128x32 bf16, 2 issues x 16B/lane ----
#pragma unroll
        for (int g = 0; g < 2; g++) {
            async_copy16(wsB + w_base + (long)(n0 + g * 64 + b_row_in_g) * CIN + k0 + b_kc,
                         (char*)BsH + g * 4096 + wave * 1024);
        }
        __syncthreads();   // drains vmcnt -> tiles visible

        // ---- fragments (swizzled ds_read) + convert A on the fly ----
        bf16x8 af[4], bfr[4];
#pragma unroll
        for (int i = 0; i < 4; i++) {
            int row = wm + i * 16 + l15;
            int r7  = row & 7;
            f32x4 a0 = *(const f32x4*)(&AsF[row * BK + ((( 2 * quad     ) ^ r7) << 2)]);
            f32x4 a1 = *(const f32x4*)(&AsF[row * BK + (((2 * quad + 1) ^ r7) << 2)]);
            bf16x8 h;
            h[0] = (bf16_t)a0[0]; h[1] = (bf16_t)a0[1];
            h[2] = (bf16_t)a0[2]; h[3] = (bf16_t)a0[3];
            h[4] = (bf16_t)a1[0]; h[5] = (bf16_t)a1[1];
            h[6] = (bf16_t)a1[2]; h[7] = (bf16_t)a1[3];
            af[i] = h;
        }
#pragma unroll
        for (int i = 0; i < 4; i++) {
            int row = wn + i * 16 + l15;
            bfr[i] = *(const bf16x8*)(&BsH[row * BK + ((quad ^ (row & 3)) << 3)]);
        }
#pragma unroll
        for (int mi = 0; mi < 4; mi++)
#pragma unroll
            for (int ni = 0; ni < 4; ni++)
                acc[mi][ni] = __builtin_amdgcn_mfma_f32_16x16x32_bf16(
                    af[mi], bfr[ni], acc[mi][ni], 0, 0, 0);
        __syncthreads();
    }

    // ---- epilogue: C layout col=lane&15, row=quad*4+reg (verified) ----
    const int c = cls[b];
    const long out_base = (long)b * NPIX * FOUT + (long)(m_t * TM) * FOUT + n0;
#pragma unroll
    for (int ni = 0; ni < 4; ni++) {
        float bv = bias[(long)c * FOUT + n0 + wn + ni * 16 + l15];
        int col = wn + ni * 16 + l15;
#pragma unroll
        for (int mi = 0; mi < 4; mi++) {
#pragma unroll
            for (int r = 0; r < 4; r++) {
                int row = wm + mi * 16 + quad * 4 + r;
                out[out_base + (long)row * FOUT + col] = acc[mi][ni][r] + bv;
            }
        }
    }
}

// ---------------------------------------------------------------------------
// Fallback (only if ws too small): naive fp32, correct but slow.
// ---------------------------------------------------------------------------
__global__ __launch_bounds__(256) void naive_kernel(
    const float* __restrict__ x, const float* __restrict__ kern,
    const float* __restrict__ bias, const int* __restrict__ cls,
    float* __restrict__ out)
{
    long i = (long)blockIdx.x * 256 + threadIdx.x;   // over 67.1M outputs
    if (i >= (long)NB * NPIX * FOUT) return;
    int f = (int)(i % FOUT);
    long p = i / FOUT;
    int b = (int)(p / NPIX);
    int c = cls[b];
    const float* xr = x + p * CIN;
    const float* wc = kern + (long)c * CIN * FOUT + f;
    float acc = 0.f;
    for (int k = 0; k < CIN; k++) acc += xr[k] * wc[(long)k * FOUT];
    out[i] = acc + bias[(long)c * FOUT + f];
}

extern "C" void kernel_launch(void* const* d_in, const int* in_sizes, int n_in,
                              void* d_out, int out_size, void* d_ws, size_t ws_size,
                              hipStream_t stream)
{
    const float* x    = (const float*)d_in[0];
    const int*   cls  = (const int*)d_in[1];
    const float* kern = (const float*)d_in[2];
    const float* bias = (const float*)d_in[3];
    float*       out  = (float*)d_out;

    const size_t ws_need = (size_t)NB * FOUT * CIN * sizeof(bf16_t);  // 16.8 MB
    if (ws_size >= ws_need) {
        bf16_t* wsB = (bf16_t*)d_ws;
        gather_w_kernel<<<dim3(FOUT / 32, CIN / 32, NB), dim3(32, 8), 0, stream>>>(
            kern, cls, wsB);
        cond_conv_gemm<<<NB * (NPIX / TM) * (FOUT / TN), 256, 0, stream>>>(
            x, wsB, bias, cls, out);
    } else {
        long n = (long)NB * NPIX * FOUT;
        naive_kernel<<<(int)((n + 255) / 256), 256, 0, stream>>>(x, kern, bias, cls, out);
    }
}